// Round 3
// baseline (2045.412 us; speedup 1.0000x reference)
//
#include <hip/hip_runtime.h>
#include <hip/hip_bf16.h>
#include <stdint.h>

#define N_NODES 2048
#define N_EDGES 32768

using short8  = __attribute__((ext_vector_type(8))) short;
using floatx4 = __attribute__((ext_vector_type(4))) float;

__device__ __forceinline__ unsigned short f2bf(float f) {
  unsigned u = __float_as_uint(f);
  unsigned r = (u + 0x7fffu + ((u >> 16) & 1u)) >> 16;
  return (unsigned short)r;
}
__device__ __forceinline__ float wave_sum(float v) {
  #pragma unroll
  for (int o = 32; o > 0; o >>= 1) v += __shfl_xor(v, o);
  return v;
}
__device__ __forceinline__ float wave_max(float v) {
  #pragma unroll
  for (int o = 32; o > 0; o >>= 1) v = fmaxf(v, __shfl_xor(v, o));
  return v;
}

// ---------------------------------------------------------------------------
// feat fp32 -> bf16 (layer-1 GEMM A operand)
// ---------------------------------------------------------------------------
__global__ __launch_bounds__(256) void cast_feat(
    const float* __restrict__ in, unsigned short* __restrict__ out, int n4)
{
  int i = blockIdx.x * 256 + threadIdx.x;
  if (i < n4) {
    float4 v = ((const float4*)in)[i];
    ushort4 o;
    o.x = f2bf(v.x); o.y = f2bf(v.y); o.z = f2bf(v.z); o.w = f2bf(v.w);
    ((ushort4*)out)[i] = o;
  }
}

// ---------------------------------------------------------------------------
// W [gridDim.z][Fin][512] (fp32) -> Wt [gridDim.z][512][Fin] (bf16), 64x64 tiles
// ---------------------------------------------------------------------------
__global__ __launch_bounds__(256) void transpose_w(
    const float* __restrict__ W, unsigned short* __restrict__ Wt, int Fin)
{
  __shared__ unsigned short tile[64][68];  // +4 pad breaks pow2 stride
  const int h  = blockIdx.z;
  const int k0 = blockIdx.x * 64;
  const int d0 = blockIdx.y * 64;
  const int t  = threadIdx.x;
  const float*    Wh  = W  + (size_t)h * Fin * 512;
  unsigned short* Wth = Wt + (size_t)h * 512 * Fin;

  const int dl = (t & 15) * 4;   // 4 d-elems (16 B fp32) per thread
  const int kr = t >> 4;
  #pragma unroll
  for (int p = 0; p < 4; ++p) {
    int k = kr + p * 16;
    float4 v = *(const float4*)(Wh + (size_t)(k0 + k) * 512 + d0 + dl);
    ushort4 b;
    b.x = f2bf(v.x); b.y = f2bf(v.y); b.z = f2bf(v.z); b.w = f2bf(v.w);
    *(ushort4*)&tile[k][dl] = b;
  }
  __syncthreads();
  const int kl = (t & 15) * 4;   // 4 k-elems, contiguous in Wt row
  const int dr = t >> 4;
  #pragma unroll
  for (int p = 0; p < 4; ++p) {
    int d = dr + p * 16;
    ushort4 v;
    v.x = tile[kl + 0][d];
    v.y = tile[kl + 1][d];
    v.z = tile[kl + 2][d];
    v.w = tile[kl + 3][d];
    *(ushort4*)(Wth + (size_t)(d0 + d) * Fin + k0 + kl) = v;
  }
}

// ---------------------------------------------------------------------------
// C[M x HD](fp32), cols [(h0+hloc)*512 + nloc ..) = A[M x K] @ Bt[hloc][512][K]
// m97 structure: 128x128 tile, BK=32, 4 waves, global_load_lds width 16.
// ---------------------------------------------------------------------------
__global__ __launch_bounds__(256) void gemm_bt(
    const unsigned short* __restrict__ A,
    const unsigned short* __restrict__ Bt,
    float* __restrict__ C, int K, int HD, int h0)
{
  __shared__ unsigned short As[128 * 32];
  __shared__ unsigned short Bs[128 * 32];
  const int tid  = threadIdx.x;
  const int w    = tid >> 6;
  const int lane = tid & 63;
  const int mt   = blockIdx.x;
  const int nt   = blockIdx.y;
  const int hloc = nt >> 2;
  const int nloc = (nt & 3) << 7;

  const unsigned short* Ab = A  + (size_t)mt * 128 * K;
  const unsigned short* Bb = Bt + (size_t)hloc * 512 * K + (size_t)nloc * K;

  const int srow = lane >> 2;          // 16 rows per staging instr
  const int scol = (lane & 3) << 3;    // 8-elem chunks
  const unsigned short* ga = Ab + (size_t)(w * 32 + srow) * K + scol;
  const unsigned short* gb = Bb + (size_t)(w * 32 + srow) * K + scol;

  floatx4 acc[4][4];
  #pragma unroll
  for (int i = 0; i < 4; ++i)
    #pragma unroll
    for (int j = 0; j < 4; ++j)
      acc[i][j] = (floatx4){0.f, 0.f, 0.f, 0.f};

  const int quad = lane >> 4;
  const int l16  = lane & 15;
  const int wm   = (w >> 1) << 6;
  const int wn   = (w & 1) << 6;

  for (int kb = 0; kb < K; kb += 32) {
    __builtin_amdgcn_global_load_lds(
        (const __attribute__((address_space(1))) void*)ga,
        (__attribute__((address_space(3))) void*)&As[w * 1024], 16, 0, 0);
    __builtin_amdgcn_global_load_lds(
        (const __attribute__((address_space(1))) void*)(ga + (size_t)16 * K),
        (__attribute__((address_space(3))) void*)&As[w * 1024 + 512], 16, 0, 0);
    __builtin_amdgcn_global_load_lds(
        (const __attribute__((address_space(1))) void*)gb,
        (__attribute__((address_space(3))) void*)&Bs[w * 1024], 16, 0, 0);
    __builtin_amdgcn_global_load_lds(
        (const __attribute__((address_space(1))) void*)(gb + (size_t)16 * K),
        (__attribute__((address_space(3))) void*)&Bs[w * 1024 + 512], 16, 0, 0);
    ga += 32; gb += 32;
    __syncthreads();

    short8 af[4], bfr[4];
    #pragma unroll
    for (int mi = 0; mi < 4; ++mi)
      af[mi] = *(const short8*)&As[(wm + mi * 16 + l16) * 32 + quad * 8];
    #pragma unroll
    for (int ni = 0; ni < 4; ++ni)
      bfr[ni] = *(const short8*)&Bs[(wn + ni * 16 + l16) * 32 + quad * 8];
    #pragma unroll
    for (int mi = 0; mi < 4; ++mi)
      #pragma unroll
      for (int ni = 0; ni < 4; ++ni)
        acc[mi][ni] = __builtin_amdgcn_mfma_f32_16x16x32_bf16(
            af[mi], bfr[ni], acc[mi][ni], 0, 0, 0);
    __syncthreads();
  }

  // C/D layout (m89/m91 verified): col = lane&15, row = quad*4 + reg
  float* Cb = C + (size_t)(mt * 128) * HD + (h0 + hloc) * 512 + nloc;
  #pragma unroll
  for (int mi = 0; mi < 4; ++mi)
    #pragma unroll
    for (int ni = 0; ni < 4; ++ni)
      #pragma unroll
      for (int r = 0; r < 4; ++r) {
        int row = wm + mi * 16 + quad * 4 + r;
        int col = wn + ni * 16 + l16;
        Cb[(size_t)row * HD + col] = acc[mi][ni][r];
      }
}

// ---------------------------------------------------------------------------
// s_src[n,h] = z[n,h,:]·a[h,0:512],  s_dst[n,h] = z[n,h,:]·a[h,512:1024]
// a is fp32. One wave per (n,h).
// ---------------------------------------------------------------------------
__global__ __launch_bounds__(64) void sdot_kernel(
    const float* __restrict__ z, const float* __restrict__ a,
    float* __restrict__ ssrc, float* __restrict__ sdst, int H)
{
  const int idx  = blockIdx.x;
  const int n    = idx / H;
  const int h    = idx % H;
  const int lane = threadIdx.x;
  const float4* zr = (const float4*)(z + (size_t)n * H * 512 + h * 512 + lane * 8);
  float4 z0 = zr[0], z1 = zr[1];
  const float4* as = (const float4*)(a + (size_t)h * 1024 + lane * 8);
  const float4* ad = (const float4*)(a + (size_t)h * 1024 + 512 + lane * 8);
  float4 a0 = as[0], a1 = as[1];
  float4 b0 = ad[0], b1 = ad[1];
  float s1 = z0.x*a0.x + z0.y*a0.y + z0.z*a0.z + z0.w*a0.w
           + z1.x*a1.x + z1.y*a1.y + z1.z*a1.z + z1.w*a1.w;
  float s2 = z0.x*b0.x + z0.y*b0.y + z0.z*b0.z + z0.w*b0.w
           + z1.x*b1.x + z1.y*b1.y + z1.z*b1.z + z1.w*b1.w;
  s1 = wave_sum(s1);
  s2 = wave_sum(s2);
  if (lane == 0) { ssrc[idx] = s1; sdst[idx] = s2; }
}

// ---------------------------------------------------------------------------
// CSR build (dst shared across all 4 layers)
// ---------------------------------------------------------------------------
__global__ void count_k(const int* __restrict__ dst, int* __restrict__ cnt) {
  int e = blockIdx.x * 256 + threadIdx.x;
  if (e < N_EDGES) atomicAdd(&cnt[dst[e]], 1);
}

__global__ __launch_bounds__(256) void scan_k(
    const int* __restrict__ cnt, int* __restrict__ offs, int* __restrict__ cur)
{
  __shared__ int part[256];
  int t = threadIdx.x;
  int loc[8]; int s = 0;
  #pragma unroll
  for (int j = 0; j < 8; ++j) { loc[j] = s; s += cnt[t * 8 + j]; }
  part[t] = s;
  __syncthreads();
  for (int d = 1; d < 256; d <<= 1) {
    int v = (t >= d) ? part[t - d] : 0;
    __syncthreads();
    part[t] += v;
    __syncthreads();
  }
  int base = (t == 0) ? 0 : part[t - 1];
  #pragma unroll
  for (int j = 0; j < 8; ++j) {
    int o = base + loc[j];
    offs[t * 8 + j] = o;
    cur[t * 8 + j]  = o;
  }
  if (t == 255) offs[2048] = part[255];
}

__global__ void scatter_k(const int* __restrict__ dst, const int* __restrict__ srcv,
                          int* __restrict__ cur, int* __restrict__ esrc) {
  int e = blockIdx.x * 256 + threadIdx.x;
  if (e < N_EDGES) {
    int p = atomicAdd(&cur[dst[e]], 1);
    esrc[p] = srcv[e];
  }
}

// ---------------------------------------------------------------------------
// Fused softmax-attention + aggregation. One wave per (n, h).
// outb (bf16, intermediate) or outf (fp32, final) — exactly one non-null.
// ---------------------------------------------------------------------------
__global__ __launch_bounds__(64) void attn_agg(
    const float* __restrict__ z, const float* __restrict__ ssrc,
    const float* __restrict__ sdst, const int* __restrict__ offs,
    const int* __restrict__ esrc, unsigned short* __restrict__ outb,
    float* __restrict__ outf, int H)
{
  const int n = blockIdx.x, h = blockIdx.y, lane = threadIdx.x;
  const int s0 = offs[n], s1 = offs[n + 1];
  const float sd = sdst[n * H + h];

  float m = -3e38f;
  for (int i = s0 + lane; i < s1; i += 64) {
    float s = ssrc[esrc[i] * H + h] + sd;
    s = (s > 0.f) ? s : s * 0.01f;
    m = fmaxf(m, s);
  }
  m = wave_max(m);

  float den = 0.f;
  for (int i = s0 + lane; i < s1; i += 64) {
    float s = ssrc[esrc[i] * H + h] + sd;
    s = (s > 0.f) ? s : s * 0.01f;
    den += __expf(s - m);
  }
  den = wave_sum(den);
  const float inv = 1.f / den;

  float acc[8] = {0.f, 0.f, 0.f, 0.f, 0.f, 0.f, 0.f, 0.f};
  const float* zb = z + (size_t)h * 512 + lane * 8;
  for (int i = s0; i < s1; ++i) {
    int se = esrc[i];
    float s = ssrc[se * H + h] + sd;
    s = (s > 0.f) ? s : s * 0.01f;
    float alpha = __expf(s - m) * inv;
    const float4* zr = (const float4*)(zb + (size_t)se * H * 512);
    float4 q0 = zr[0], q1 = zr[1];
    acc[0] += alpha * q0.x; acc[1] += alpha * q0.y;
    acc[2] += alpha * q0.z; acc[3] += alpha * q0.w;
    acc[4] += alpha * q1.x; acc[5] += alpha * q1.y;
    acc[6] += alpha * q1.z; acc[7] += alpha * q1.w;
  }

  const size_t base = (size_t)n * H * 512 + h * 512 + lane * 8;
  if (outf) {
    float4 o0 = {acc[0], acc[1], acc[2], acc[3]};
    float4 o1 = {acc[4], acc[5], acc[6], acc[7]};
    *(float4*)(outf + base)     = o0;
    *(float4*)(outf + base + 4) = o1;
  } else {
    uint4 pk;
    pk.x = (unsigned)f2bf(acc[0]) | ((unsigned)f2bf(acc[1]) << 16);
    pk.y = (unsigned)f2bf(acc[2]) | ((unsigned)f2bf(acc[3]) << 16);
    pk.z = (unsigned)f2bf(acc[4]) | ((unsigned)f2bf(acc[5]) << 16);
    pk.w = (unsigned)f2bf(acc[6]) | ((unsigned)f2bf(acc[7]) << 16);
    *(uint4*)(outb + base) = pk;
  }
}

// ---------------------------------------------------------------------------
extern "C" void kernel_launch(void* const* d_in, const int* in_sizes, int n_in,
                              void* d_out, int out_size, void* d_ws, size_t ws_size,
                              hipStream_t stream)
{
  (void)in_sizes; (void)n_in; (void)out_size; (void)ws_size;
  // Reference dtypes: all float arrays are fp32; src/dst int32; output fp32.
  const float* feat = (const float*)d_in[0];
  const float* W1   = (const float*)d_in[1];
  const float* a1   = (const float*)d_in[2];
  const float* W2   = (const float*)d_in[3];
  const float* a2   = (const float*)d_in[4];
  const float* W3   = (const float*)d_in[5];
  const float* a3   = (const float*)d_in[6];
  const float* W4   = (const float*)d_in[7];
  const float* a4   = (const float*)d_in[8];
  const int* src = (const int*)d_in[9];
  const int* dst = (const int*)d_in[10];
  float* out = (float*)d_out;

  // Workspace layout — ~204 MiB total.
  char* ws = (char*)d_ws;
  unsigned short* wt = (unsigned short*)(ws + 0);          //  67,108,864 B (8 heads)
  float* z           = (float*)(ws + 67108864);            //  67,108,864 B
  unsigned short* x1 = (unsigned short*)(ws + 134217728);  //  33,554,432 B
  unsigned short* x2 = (unsigned short*)(ws + 167772160);  //  33,554,432 B
  unsigned short* x0 = (unsigned short*)(ws + 201326592);  //   2,097,152 B
  float* ssrc        = (float*)(ws + 203423744);           //     131,072 B
  float* sdst        = (float*)(ws + 203554816);           //     131,072 B
  int* cnt           = (int*)(ws + 203685888);
  int* offs          = (int*)(ws + 203694080);
  int* cur           = (int*)(ws + 203702528);
  int* esrc          = (int*)(ws + 203710720);             //     131,072 B

  // CSR by dst (constant across layers)
  hipMemsetAsync(cnt, 0, N_NODES * sizeof(int), stream);
  count_k<<<N_EDGES / 256, 256, 0, stream>>>(dst, cnt);
  scan_k<<<1, 256, 0, stream>>>(cnt, offs, cur);
  scatter_k<<<N_EDGES / 256, 256, 0, stream>>>(dst, src, cur, esrc);

  // feat fp32 -> bf16
  cast_feat<<<1024, 256, 0, stream>>>(feat, x0, N_NODES * 512 / 4);

  // Layer 1: Fin=512, H=16 (wt all 16 heads = 8.4 MB)
  transpose_w<<<dim3(8, 8, 16), 256, 0, stream>>>(W1, wt, 512);
  gemm_bt<<<dim3(16, 64), 256, 0, stream>>>(x0, wt, z, 512, 8192, 0);
  sdot_kernel<<<N_NODES * 16, 64, 0, stream>>>(z, a1, ssrc, sdst, 16);
  attn_agg<<<dim3(N_NODES, 16), 64, 0, stream>>>(z, ssrc, sdst, offs, esrc,
                                                 x1, nullptr, 16);

  // Layer 2: Fin=8192, H=16 — two 8-head groups through wt
  for (int g = 0; g < 2; ++g) {
    transpose_w<<<dim3(128, 8, 8), 256, 0, stream>>>(
        W2 + (size_t)g * 8 * 8192 * 512, wt, 8192);
    gemm_bt<<<dim3(16, 32), 256, 0, stream>>>(x1, wt, z, 8192, 8192, g * 8);
  }
  sdot_kernel<<<N_NODES * 16, 64, 0, stream>>>(z, a2, ssrc, sdst, 16);
  attn_agg<<<dim3(N_NODES, 16), 64, 0, stream>>>(z, ssrc, sdst, offs, esrc,
                                                 x2, nullptr, 16);

  // Layer 3: Fin=8192, H=16
  for (int g = 0; g < 2; ++g) {
    transpose_w<<<dim3(128, 8, 8), 256, 0, stream>>>(
        W3 + (size_t)g * 8 * 8192 * 512, wt, 8192);
    gemm_bt<<<dim3(16, 32), 256, 0, stream>>>(x2, wt, z, 8192, 8192, g * 8);
  }
  sdot_kernel<<<N_NODES * 16, 64, 0, stream>>>(z, a3, ssrc, sdst, 16);
  attn_agg<<<dim3(N_NODES, 16), 64, 0, stream>>>(z, ssrc, sdst, offs, esrc,
                                                 x1, nullptr, 16);

  // Layer 4: Fin=8192, H=1 — fp32 output to d_out
  transpose_w<<<dim3(128, 8, 1), 256, 0, stream>>>(W4, wt, 8192);
  gemm_bt<<<dim3(16, 4), 256, 0, stream>>>(x1, wt, z, 8192, 512, 0);
  sdot_kernel<<<N_NODES, 64, 0, stream>>>(z, a4, ssrc, sdst, 1);
  attn_agg<<<dim3(N_NODES, 1), 64, 0, stream>>>(z, ssrc, sdst, offs, esrc,
                                                nullptr, out, 1);
}